// Round 2
// baseline (1526.644 us; speedup 1.0000x reference)
//
#include <hip/hip_runtime.h>

// ---------------------------------------------------------------------------
// GCN 3-layer: h = relu(Agg(dinv*x@W1)+b1); h = relu(Agg(dinv*h@W2)+b2);
//              out = Agg(dinv*h@W3)+b3
// Agg(y)[d] = dinv[d] * ( sum_{e: dst=d} y[src_e] + y[d] )   (self-loop folded)
// where y already carries the dinv[src] factor.
// Round 2: correctness bisection — transform1 and aggregate replaced with
// obviously-correct simple versions; CSR build + transform2/3 kept from R1.
// ---------------------------------------------------------------------------

__global__ __launch_bounds__(256) void zero_i32(int* p, int n) {
    int i = blockIdx.x * 256 + threadIdx.x;
    if (i < n) p[i] = 0;
}

__global__ __launch_bounds__(256) void count_deg(const int* __restrict__ dst,
                                                 int* __restrict__ deg, int e) {
    int i = blockIdx.x * 256 + threadIdx.x;
    if (i < e) atomicAdd(&deg[dst[i]], 1);
}

// ---- scan: 1024 elems/block, 3 kernels ----
__global__ __launch_bounds__(256) void scan_partial(const int* __restrict__ deg,
                                                    int* __restrict__ bsums, int n) {
    __shared__ int sd[256];
    int t = threadIdx.x;
    int base = blockIdx.x * 1024 + t * 4;
    int s = 0;
#pragma unroll
    for (int j = 0; j < 4; j++)
        if (base + j < n) s += deg[base + j];
    sd[t] = s;
    __syncthreads();
    for (int off = 128; off > 0; off >>= 1) {
        if (t < off) sd[t] += sd[t + off];
        __syncthreads();
    }
    if (t == 0) bsums[blockIdx.x] = sd[0];
}

__global__ __launch_bounds__(256) void scan_blocksums(int* __restrict__ bs, int nb,
                                                      int* __restrict__ rowptr, int n) {
    __shared__ int s[256];
    int t = threadIdx.x;
    s[t] = (t < nb) ? bs[t] : 0;
    __syncthreads();
    for (int off = 1; off < 256; off <<= 1) {
        int u = (t >= off) ? s[t - off] : 0;
        __syncthreads();
        s[t] += u;
        __syncthreads();
    }
    if (t < nb) bs[t] = (t > 0) ? s[t - 1] : 0;  // exclusive block offsets
    if (t == 0) rowptr[n] = s[255];              // total = E
}

__global__ __launch_bounds__(256) void scan_final(const int* __restrict__ deg,
                                                  const int* __restrict__ bs,
                                                  int* __restrict__ rowptr,
                                                  int* __restrict__ fillc,
                                                  float* __restrict__ dinv, int n) {
    __shared__ int sd[256];
    int t = threadIdx.x;
    int base = blockIdx.x * 1024 + t * 4;
    int v0 = 0, v1 = 0, v2 = 0, v3 = 0;
    if (base + 0 < n) v0 = deg[base + 0];
    if (base + 1 < n) v1 = deg[base + 1];
    if (base + 2 < n) v2 = deg[base + 2];
    if (base + 3 < n) v3 = deg[base + 3];
    sd[t] = v0 + v1 + v2 + v3;
    __syncthreads();
    for (int off = 1; off < 256; off <<= 1) {
        int u = (t >= off) ? sd[t - off] : 0;
        __syncthreads();
        sd[t] += u;
        __syncthreads();
    }
    int run = bs[blockIdx.x] + ((t > 0) ? sd[t - 1] : 0);
    if (base + 0 < n) { rowptr[base + 0] = run; fillc[base + 0] = run; dinv[base + 0] = rsqrtf((float)(v0 + 1)); run += v0; }
    if (base + 1 < n) { rowptr[base + 1] = run; fillc[base + 1] = run; dinv[base + 1] = rsqrtf((float)(v1 + 1)); run += v1; }
    if (base + 2 < n) { rowptr[base + 2] = run; fillc[base + 2] = run; dinv[base + 2] = rsqrtf((float)(v2 + 1)); run += v2; }
    if (base + 3 < n) { rowptr[base + 3] = run; fillc[base + 3] = run; dinv[base + 3] = rsqrtf((float)(v3 + 1)); run += v3; }
}

__global__ __launch_bounds__(256) void fill_csr(const int* __restrict__ src,
                                                const int* __restrict__ dst,
                                                int* __restrict__ fillc,
                                                int* __restrict__ colidx, int e) {
    int i = blockIdx.x * 256 + threadIdx.x;
    if (i < e) {
        int d = dst[i];
        int p = atomicAdd(&fillc[d], 1);
        colidx[p] = src[i];
    }
}

// ---- transform 1 (simple): h1 = dinv .* (x @ W1), x:(n,512) W1:(512,64) ----
// 8 rows per 256-thread block. Stage 8 full rows in LDS (16 KB), each thread
// computes 2 output columns with a straight k-loop. No transposes, no tiling.
__global__ __launch_bounds__(256) void transform1_simple(const float* __restrict__ x,
                                                         const float* __restrict__ W1,
                                                         const float* __restrict__ dinv,
                                                         float* __restrict__ h1, int n) {
    __shared__ float rows[8 * 512];
    const int t = threadIdx.x;
    const int row0 = blockIdx.x * 8;
#pragma unroll
    for (int i = 0; i < 4; i++) {          // 1024 float4 total, 4 per thread
        int c = t + i * 256;               // float4 index
        int r = c >> 7;                    // 128 float4 per row
        int k4 = (c & 127) << 2;
        float4 v = make_float4(0.f, 0.f, 0.f, 0.f);
        if (row0 + r < n) v = *(const float4*)&x[(size_t)(row0 + r) * 512 + k4];
        *(float4*)&rows[r * 512 + k4] = v;
    }
    __syncthreads();
    const int r = t >> 5;                  // 0..7
    const int c0 = (t & 31) * 2;           // 0..62
    float a0 = 0.f, a1 = 0.f;
    for (int k = 0; k < 512; k++) {
        float a = rows[r * 512 + k];
        float2 w = *(const float2*)&W1[(size_t)k * 64 + c0];
        a0 += a * w.x;
        a1 += a * w.y;
    }
    int row = row0 + r;
    if (row < n) {
        float s = dinv[row];
        h1[(size_t)row * 64 + c0 + 0] = a0 * s;
        h1[(size_t)row * 64 + c0 + 1] = a1 * s;
    }
}

// ---- transform 2: h2 = dinv .* (g1 @ W2), g1:(n,64) W2:(64,32). 8 rows/block ----
__global__ __launch_bounds__(256) void transform2(const float* __restrict__ g1,
                                                  const float* __restrict__ W2,
                                                  const float* __restrict__ dinv,
                                                  float* __restrict__ h2, int n) {
    __shared__ float rows[8 * 64];
    __shared__ float W2s[64 * 32];
    int t = threadIdx.x;
    int row0 = blockIdx.x * 8;
    if (t < 128) {
        int r = t >> 4, k4 = (t & 15) << 2;
        int grow = row0 + r;
        float4 v = make_float4(0.f, 0.f, 0.f, 0.f);
        if (grow < n) v = *(const float4*)&g1[(size_t)grow * 64 + k4];
        *(float4*)&rows[r * 64 + k4] = v;
    }
#pragma unroll
    for (int i = 0; i < 2; i++) {
        int c = t + i * 256;  // 512 float4 = 2048 floats
        *(float4*)&W2s[c * 4] = *(const float4*)&W2[c * 4];
    }
    __syncthreads();
    int lr = t >> 5, col = t & 31;
    int row = row0 + lr;
    float acc = 0.f;
#pragma unroll
    for (int k4 = 0; k4 < 64; k4 += 4) {
        float4 a = *(const float4*)&rows[lr * 64 + k4];
        acc += a.x * W2s[(k4 + 0) * 32 + col];
        acc += a.y * W2s[(k4 + 1) * 32 + col];
        acc += a.z * W2s[(k4 + 2) * 32 + col];
        acc += a.w * W2s[(k4 + 3) * 32 + col];
    }
    if (row < n) h2[(size_t)row * 32 + col] = dinv[row] * acc;
}

// ---- transform 3: h3 = dinv .* (g2 @ W3), g2:(n,32) W3:(32,4). thread/row ----
__global__ __launch_bounds__(256) void transform3(const float* __restrict__ g2,
                                                  const float* __restrict__ W3,
                                                  const float* __restrict__ dinv,
                                                  float* __restrict__ h3, int n) {
    __shared__ float W3s[128];
    int t = threadIdx.x;
    if (t < 128) W3s[t] = W3[t];
    __syncthreads();
    int row = blockIdx.x * 256 + t;
    if (row >= n) return;
    float a0 = 0.f, a1 = 0.f, a2 = 0.f, a3 = 0.f;
    const float4* rp = (const float4*)&g2[(size_t)row * 32];
#pragma unroll
    for (int kk = 0; kk < 8; kk++) {
        float4 v = rp[kk];
        float4 w0 = *(const float4*)&W3s[(4 * kk + 0) * 4];
        float4 w1 = *(const float4*)&W3s[(4 * kk + 1) * 4];
        float4 w2 = *(const float4*)&W3s[(4 * kk + 2) * 4];
        float4 w3 = *(const float4*)&W3s[(4 * kk + 3) * 4];
        a0 += v.x * w0.x + v.y * w1.x + v.z * w2.x + v.w * w3.x;
        a1 += v.x * w0.y + v.y * w1.y + v.z * w2.y + v.w * w3.y;
        a2 += v.x * w0.z + v.y * w1.z + v.z * w2.z + v.w * w3.z;
        a3 += v.x * w0.w + v.y * w1.w + v.z * w2.w + v.w * w3.w;
    }
    float s = dinv[row];
    float4 o = make_float4(a0 * s, a1 * s, a2 * s, a3 * s);
    *(float4*)&h3[(size_t)row * 4] = o;
}

// ---- aggregation (simple): one wave per node, lane = feature, no shuffles ----
// out[d][f] = (RELU?)( dinv[d] * (sum_{e} h[col[e]][f] + h[d][f]) + bias[f] )
template <int F, bool RELU>
__global__ __launch_bounds__(256) void aggregate_simple(const float* __restrict__ h,
                                                        const int* __restrict__ rowptr,
                                                        const int* __restrict__ colidx,
                                                        const float* __restrict__ dinv,
                                                        const float* __restrict__ bias,
                                                        float* __restrict__ out, int n) {
    int node = (blockIdx.x * 256 + threadIdx.x) >> 6;  // one wave per node
    int lane = threadIdx.x & 63;
    if (node >= n) return;
    if (lane >= F) return;                             // idle lanes for F<64
    float acc = h[(size_t)node * F + lane];            // self loop
    int r0 = rowptr[node], r1 = rowptr[node + 1];
    for (int e = r0; e < r1; e++) {
        int c = colidx[e];                             // wave-uniform
        acc += h[(size_t)c * F + lane];
    }
    float v = dinv[node] * acc + bias[lane];
    if (RELU) v = fmaxf(v, 0.f);
    out[(size_t)node * F + lane] = v;
}

extern "C" void kernel_launch(void* const* d_in, const int* in_sizes, int n_in,
                              void* d_out, int out_size, void* d_ws, size_t ws_size,
                              hipStream_t stream) {
    const float* x  = (const float*)d_in[0];
    const int*   ei = (const int*)d_in[1];
    const float* W1 = (const float*)d_in[2];
    const float* b1 = (const float*)d_in[3];
    const float* W2 = (const float*)d_in[4];
    const float* b2 = (const float*)d_in[5];
    const float* W3 = (const float*)d_in[6];
    const float* b3 = (const float*)d_in[7];
    const int n = in_sizes[0] / 512;  // 100000
    const int e = in_sizes[1] / 2;    // 1600000
    const int* src = ei;
    const int* dst = ei + e;
    float* out = (float*)d_out;

    char* p = (char*)d_ws;
    auto alloc = [&](size_t bytes) {
        void* r = (void*)p;
        p += (bytes + 255) & ~(size_t)255;
        return r;
    };
    int*   deg    = (int*)alloc((size_t)n * 4);
    int*   rowptr = (int*)alloc((size_t)(n + 1) * 4);
    int*   fillc  = (int*)alloc((size_t)n * 4);
    int*   bsums  = (int*)alloc(1024);
    int*   colidx = (int*)alloc((size_t)e * 4);
    float* dinv   = (float*)alloc((size_t)n * 4);
    float* bufA   = (float*)alloc((size_t)n * 64 * 4);
    float* bufB   = (float*)alloc((size_t)n * 64 * 4);

    const int NB = (n + 1023) / 1024;  // 98 scan blocks
    const int AGG_BLOCKS = (int)(((size_t)n * 64 + 255) / 256);  // one wave/node

    zero_i32<<<dim3((n + 255) / 256), dim3(256), 0, stream>>>(deg, n);
    count_deg<<<dim3((e + 255) / 256), dim3(256), 0, stream>>>(dst, deg, e);
    scan_partial<<<dim3(NB), dim3(256), 0, stream>>>(deg, bsums, n);
    scan_blocksums<<<dim3(1), dim3(256), 0, stream>>>(bsums, NB, rowptr, n);
    scan_final<<<dim3(NB), dim3(256), 0, stream>>>(deg, bsums, rowptr, fillc, dinv, n);
    fill_csr<<<dim3((e + 255) / 256), dim3(256), 0, stream>>>(src, dst, fillc, colidx, e);

    // layer 1: transform (n,512)->(n,64), aggregate, relu
    transform1_simple<<<dim3((n + 7) / 8), dim3(256), 0, stream>>>(x, W1, dinv, bufA, n);
    aggregate_simple<64, true><<<dim3(AGG_BLOCKS), dim3(256), 0, stream>>>(bufA, rowptr, colidx, dinv, b1, bufB, n);
    // layer 2: (n,64)->(n,32)
    transform2<<<dim3((n + 7) / 8), dim3(256), 0, stream>>>(bufB, W2, dinv, bufA, n);
    aggregate_simple<32, true><<<dim3(AGG_BLOCKS), dim3(256), 0, stream>>>(bufA, rowptr, colidx, dinv, b2, bufB, n);
    // layer 3: (n,32)->(n,4), no relu
    transform3<<<dim3((n + 255) / 256), dim3(256), 0, stream>>>(bufB, W3, dinv, bufA, n);
    aggregate_simple<4, false><<<dim3(AGG_BLOCKS), dim3(256), 0, stream>>>(bufA, rowptr, colidx, dinv, b3, out, n);
}

// Round 3
// 788.519 us; speedup vs baseline: 1.9361x; 1.9361x over previous
//
#include <hip/hip_runtime.h>

// ---------------------------------------------------------------------------
// GCN 3-layer: h = relu(Agg(dinv*x@W1)+b1); h = relu(Agg(dinv*h@W2)+b2);
//              out = Agg(dinv*h@W3)+b3
// Agg(y)[d] = dinv[d] * ( sum_{e: dst=d} y[src_e] + y[d] )   (self-loop folded)
// where y already carries the dinv[src] factor.
// R3: transform1 -> 64x64 tiled GEMM (4x4 reg blocking, BK=32);
//     aggregate -> F-lane group per node (full lane utilization).
// ---------------------------------------------------------------------------

__global__ __launch_bounds__(256) void zero_i32(int* p, int n) {
    int i = blockIdx.x * 256 + threadIdx.x;
    if (i < n) p[i] = 0;
}

__global__ __launch_bounds__(256) void count_deg(const int* __restrict__ dst,
                                                 int* __restrict__ deg, int e) {
    int i = blockIdx.x * 256 + threadIdx.x;
    if (i < e) atomicAdd(&deg[dst[i]], 1);
}

// ---- scan: 1024 elems/block, 3 kernels ----
__global__ __launch_bounds__(256) void scan_partial(const int* __restrict__ deg,
                                                    int* __restrict__ bsums, int n) {
    __shared__ int sd[256];
    int t = threadIdx.x;
    int base = blockIdx.x * 1024 + t * 4;
    int s = 0;
#pragma unroll
    for (int j = 0; j < 4; j++)
        if (base + j < n) s += deg[base + j];
    sd[t] = s;
    __syncthreads();
    for (int off = 128; off > 0; off >>= 1) {
        if (t < off) sd[t] += sd[t + off];
        __syncthreads();
    }
    if (t == 0) bsums[blockIdx.x] = sd[0];
}

__global__ __launch_bounds__(256) void scan_blocksums(int* __restrict__ bs, int nb,
                                                      int* __restrict__ rowptr, int n) {
    __shared__ int s[256];
    int t = threadIdx.x;
    s[t] = (t < nb) ? bs[t] : 0;
    __syncthreads();
    for (int off = 1; off < 256; off <<= 1) {
        int u = (t >= off) ? s[t - off] : 0;
        __syncthreads();
        s[t] += u;
        __syncthreads();
    }
    if (t < nb) bs[t] = (t > 0) ? s[t - 1] : 0;  // exclusive block offsets
    if (t == 0) rowptr[n] = s[255];              // total = E
}

__global__ __launch_bounds__(256) void scan_final(const int* __restrict__ deg,
                                                  const int* __restrict__ bs,
                                                  int* __restrict__ rowptr,
                                                  int* __restrict__ fillc,
                                                  float* __restrict__ dinv, int n) {
    __shared__ int sd[256];
    int t = threadIdx.x;
    int base = blockIdx.x * 1024 + t * 4;
    int v0 = 0, v1 = 0, v2 = 0, v3 = 0;
    if (base + 0 < n) v0 = deg[base + 0];
    if (base + 1 < n) v1 = deg[base + 1];
    if (base + 2 < n) v2 = deg[base + 2];
    if (base + 3 < n) v3 = deg[base + 3];
    sd[t] = v0 + v1 + v2 + v3;
    __syncthreads();
    for (int off = 1; off < 256; off <<= 1) {
        int u = (t >= off) ? sd[t - off] : 0;
        __syncthreads();
        sd[t] += u;
        __syncthreads();
    }
    int run = bs[blockIdx.x] + ((t > 0) ? sd[t - 1] : 0);
    if (base + 0 < n) { rowptr[base + 0] = run; fillc[base + 0] = run; dinv[base + 0] = rsqrtf((float)(v0 + 1)); run += v0; }
    if (base + 1 < n) { rowptr[base + 1] = run; fillc[base + 1] = run; dinv[base + 1] = rsqrtf((float)(v1 + 1)); run += v1; }
    if (base + 2 < n) { rowptr[base + 2] = run; fillc[base + 2] = run; dinv[base + 2] = rsqrtf((float)(v2 + 1)); run += v2; }
    if (base + 3 < n) { rowptr[base + 3] = run; fillc[base + 3] = run; dinv[base + 3] = rsqrtf((float)(v3 + 1)); run += v3; }
}

__global__ __launch_bounds__(256) void fill_csr(const int* __restrict__ src,
                                                const int* __restrict__ dst,
                                                int* __restrict__ fillc,
                                                int* __restrict__ colidx, int e) {
    int i = blockIdx.x * 256 + threadIdx.x;
    if (i < e) {
        int d = dst[i];
        int p = atomicAdd(&fillc[d], 1);
        colidx[p] = src[i];
    }
}

// ---- transform 1 (tiled): h1 = dinv .* (x @ W1), x:(n,512) W1:(512,64) ----
// 64 rows x 64 cols per 256-thread block; BK=32; 4x4 accumulators per thread.
// As[k][m] (transposed x tile, row stride 68 floats = 272B, 16B aligned).
// Bs[k][j] (W1 tile). Compute reads are float4 from both.
__global__ __launch_bounds__(256) void transform1_tiled(const float* __restrict__ x,
                                                        const float* __restrict__ W1,
                                                        const float* __restrict__ dinv,
                                                        float* __restrict__ h1, int n) {
    __shared__ float As[32 * 68];  // As[k*68 + m]
    __shared__ float Bs[32 * 64];  // Bs[k*64 + j]
    const int t = threadIdx.x;
    const int row0 = blockIdx.x * 64;
    const int mt = (t >> 4) * 4;   // 0,4,...,60  (output row group)
    const int jt = (t & 15) * 4;   // 0,4,...,60  (output col group)
    float acc[4][4] = {};

    for (int k0 = 0; k0 < 512; k0 += 32) {
        __syncthreads();
        // stage A: 64 rows x 32 k = 512 float4 chunks; chunk c -> row m=c>>3,
        // k-offset kc=(c&7)*4; scatter-transpose into As[kc+q][m].
#pragma unroll
        for (int i = 0; i < 2; i++) {
            int c = t + i * 256;
            int m = c >> 3;
            int kc = (c & 7) << 2;
            int grow = row0 + m;
            float4 v = make_float4(0.f, 0.f, 0.f, 0.f);
            if (grow < n) v = *(const float4*)&x[(size_t)grow * 512 + k0 + kc];
            As[(kc + 0) * 68 + m] = v.x;
            As[(kc + 1) * 68 + m] = v.y;
            As[(kc + 2) * 68 + m] = v.z;
            As[(kc + 3) * 68 + m] = v.w;
        }
        // stage B: 32 k-rows x 64 cols = 512 float4 chunks; kr=c>>4, jc=(c&15)*4
#pragma unroll
        for (int i = 0; i < 2; i++) {
            int c = t + i * 256;
            int kr = c >> 4;
            int jc = (c & 15) << 2;
            *(float4*)&Bs[kr * 64 + jc] = *(const float4*)&W1[(size_t)(k0 + kr) * 64 + jc];
        }
        __syncthreads();
#pragma unroll
        for (int kk = 0; kk < 32; kk++) {
            float4 a = *(const float4*)&As[kk * 68 + mt];
            float4 b = *(const float4*)&Bs[kk * 64 + jt];
            acc[0][0] += a.x * b.x; acc[0][1] += a.x * b.y; acc[0][2] += a.x * b.z; acc[0][3] += a.x * b.w;
            acc[1][0] += a.y * b.x; acc[1][1] += a.y * b.y; acc[1][2] += a.y * b.z; acc[1][3] += a.y * b.w;
            acc[2][0] += a.z * b.x; acc[2][1] += a.z * b.y; acc[2][2] += a.z * b.z; acc[2][3] += a.z * b.w;
            acc[3][0] += a.w * b.x; acc[3][1] += a.w * b.y; acc[3][2] += a.w * b.z; acc[3][3] += a.w * b.w;
        }
    }
#pragma unroll
    for (int i = 0; i < 4; i++) {
        int row = row0 + mt + i;
        if (row < n) {
            float s = dinv[row];
            float4 o = make_float4(acc[i][0] * s, acc[i][1] * s, acc[i][2] * s, acc[i][3] * s);
            *(float4*)&h1[(size_t)row * 64 + jt] = o;
        }
    }
}

// ---- transform 2: h2 = dinv .* (g1 @ W2), g1:(n,64) W2:(64,32). 8 rows/block ----
__global__ __launch_bounds__(256) void transform2(const float* __restrict__ g1,
                                                  const float* __restrict__ W2,
                                                  const float* __restrict__ dinv,
                                                  float* __restrict__ h2, int n) {
    __shared__ float rows[8 * 64];
    __shared__ float W2s[64 * 32];
    int t = threadIdx.x;
    int row0 = blockIdx.x * 8;
    if (t < 128) {
        int r = t >> 4, k4 = (t & 15) << 2;
        int grow = row0 + r;
        float4 v = make_float4(0.f, 0.f, 0.f, 0.f);
        if (grow < n) v = *(const float4*)&g1[(size_t)grow * 64 + k4];
        *(float4*)&rows[r * 64 + k4] = v;
    }
#pragma unroll
    for (int i = 0; i < 2; i++) {
        int c = t + i * 256;  // 512 float4 = 2048 floats
        *(float4*)&W2s[c * 4] = *(const float4*)&W2[c * 4];
    }
    __syncthreads();
    int lr = t >> 5, col = t & 31;
    int row = row0 + lr;
    float acc = 0.f;
#pragma unroll
    for (int k4 = 0; k4 < 64; k4 += 4) {
        float4 a = *(const float4*)&rows[lr * 64 + k4];
        acc += a.x * W2s[(k4 + 0) * 32 + col];
        acc += a.y * W2s[(k4 + 1) * 32 + col];
        acc += a.z * W2s[(k4 + 2) * 32 + col];
        acc += a.w * W2s[(k4 + 3) * 32 + col];
    }
    if (row < n) h2[(size_t)row * 32 + col] = dinv[row] * acc;
}

// ---- transform 3: h3 = dinv .* (g2 @ W3), g2:(n,32) W3:(32,4). thread/row ----
__global__ __launch_bounds__(256) void transform3(const float* __restrict__ g2,
                                                  const float* __restrict__ W3,
                                                  const float* __restrict__ dinv,
                                                  float* __restrict__ h3, int n) {
    __shared__ float W3s[128];
    int t = threadIdx.x;
    if (t < 128) W3s[t] = W3[t];
    __syncthreads();
    int row = blockIdx.x * 256 + t;
    if (row >= n) return;
    float a0 = 0.f, a1 = 0.f, a2 = 0.f, a3 = 0.f;
    const float4* rp = (const float4*)&g2[(size_t)row * 32];
#pragma unroll
    for (int kk = 0; kk < 8; kk++) {
        float4 v = rp[kk];
        float4 w0 = *(const float4*)&W3s[(4 * kk + 0) * 4];
        float4 w1 = *(const float4*)&W3s[(4 * kk + 1) * 4];
        float4 w2 = *(const float4*)&W3s[(4 * kk + 2) * 4];
        float4 w3 = *(const float4*)&W3s[(4 * kk + 3) * 4];
        a0 += v.x * w0.x + v.y * w1.x + v.z * w2.x + v.w * w3.x;
        a1 += v.x * w0.y + v.y * w1.y + v.z * w2.y + v.w * w3.y;
        a2 += v.x * w0.z + v.y * w1.z + v.z * w2.z + v.w * w3.z;
        a3 += v.x * w0.w + v.y * w1.w + v.z * w2.w + v.w * w3.w;
    }
    float s = dinv[row];
    float4 o = make_float4(a0 * s, a1 * s, a2 * s, a3 * s);
    *(float4*)&h3[(size_t)row * 4] = o;
}

// ---- aggregation (grouped): one F-lane group per node, all lanes active ----
// out[d][f] = (RELU?)( dinv[d] * (sum_{e} h[col[e]][f] + h[d][f]) + bias[f] )
template <int F, bool RELU>
__global__ __launch_bounds__(256) void aggregate_grouped(const float* __restrict__ h,
                                                         const int* __restrict__ rowptr,
                                                         const int* __restrict__ colidx,
                                                         const float* __restrict__ dinv,
                                                         const float* __restrict__ bias,
                                                         float* __restrict__ out, int n) {
    int tid = blockIdx.x * 256 + threadIdx.x;
    int node = tid / F;                 // F is a power of two -> shift
    int f = tid & (F - 1);
    if (node >= n) return;
    float acc = h[(size_t)node * F + f];  // self loop
    int r0 = rowptr[node], r1 = rowptr[node + 1];
    for (int e = r0; e < r1; e++) {
        int c = colidx[e];              // group-uniform (broadcast within group)
        acc += h[(size_t)c * F + f];
    }
    float v = dinv[node] * acc + bias[f];
    if (RELU) v = fmaxf(v, 0.f);
    out[(size_t)node * F + f] = v;
}

extern "C" void kernel_launch(void* const* d_in, const int* in_sizes, int n_in,
                              void* d_out, int out_size, void* d_ws, size_t ws_size,
                              hipStream_t stream) {
    const float* x  = (const float*)d_in[0];
    const int*   ei = (const int*)d_in[1];
    const float* W1 = (const float*)d_in[2];
    const float* b1 = (const float*)d_in[3];
    const float* W2 = (const float*)d_in[4];
    const float* b2 = (const float*)d_in[5];
    const float* W3 = (const float*)d_in[6];
    const float* b3 = (const float*)d_in[7];
    const int n = in_sizes[0] / 512;  // 100000
    const int e = in_sizes[1] / 2;    // 1600000
    const int* src = ei;
    const int* dst = ei + e;
    float* out = (float*)d_out;

    char* p = (char*)d_ws;
    auto alloc = [&](size_t bytes) {
        void* r = (void*)p;
        p += (bytes + 255) & ~(size_t)255;
        return r;
    };
    int*   deg    = (int*)alloc((size_t)n * 4);
    int*   rowptr = (int*)alloc((size_t)(n + 1) * 4);
    int*   fillc  = (int*)alloc((size_t)n * 4);
    int*   bsums  = (int*)alloc(1024);
    int*   colidx = (int*)alloc((size_t)e * 4);
    float* dinv   = (float*)alloc((size_t)n * 4);
    float* bufA   = (float*)alloc((size_t)n * 64 * 4);
    float* bufB   = (float*)alloc((size_t)n * 64 * 4);

    const int NB = (n + 1023) / 1024;  // 98 scan blocks

    zero_i32<<<dim3((n + 255) / 256), dim3(256), 0, stream>>>(deg, n);
    count_deg<<<dim3((e + 255) / 256), dim3(256), 0, stream>>>(dst, deg, e);
    scan_partial<<<dim3(NB), dim3(256), 0, stream>>>(deg, bsums, n);
    scan_blocksums<<<dim3(1), dim3(256), 0, stream>>>(bsums, NB, rowptr, n);
    scan_final<<<dim3(NB), dim3(256), 0, stream>>>(deg, bsums, rowptr, fillc, dinv, n);
    fill_csr<<<dim3((e + 255) / 256), dim3(256), 0, stream>>>(src, dst, fillc, colidx, e);

    // layer 1: transform (n,512)->(n,64), aggregate, relu
    transform1_tiled<<<dim3((n + 63) / 64), dim3(256), 0, stream>>>(x, W1, dinv, bufA, n);
    aggregate_grouped<64, true><<<dim3((int)(((size_t)n * 64 + 255) / 256)), dim3(256), 0, stream>>>(bufA, rowptr, colidx, dinv, b1, bufB, n);
    // layer 2: (n,64)->(n,32)
    transform2<<<dim3((n + 7) / 8), dim3(256), 0, stream>>>(bufB, W2, dinv, bufA, n);
    aggregate_grouped<32, true><<<dim3((int)(((size_t)n * 32 + 255) / 256)), dim3(256), 0, stream>>>(bufA, rowptr, colidx, dinv, b2, bufB, n);
    // layer 3: (n,32)->(n,4), no relu
    transform3<<<dim3((n + 255) / 256), dim3(256), 0, stream>>>(bufB, W3, dinv, bufA, n);
    aggregate_grouped<4, false><<<dim3((int)(((size_t)n * 4 + 255) / 256)), dim3(256), 0, stream>>>(bufA, rowptr, colidx, dinv, b3, out, n);
}

// Round 4
// 669.689 us; speedup vs baseline: 2.2796x; 1.1774x over previous
//
#include <hip/hip_runtime.h>

// ---------------------------------------------------------------------------
// GCN 3-layer: h = relu(Agg(dinv*x@W1)+b1); h = relu(Agg(dinv*h@W2)+b2);
//              out = Agg(dinv*h@W3)+b3
// Agg(y)[d] = dinv[d] * ( sum_{e: dst=d} y[src_e] + y[d] )   (self-loop folded)
// where y already carries the dinv[src] factor.
// R4: aggregate -> 8-way edge-unrolled independent gathers (break the
//     dependent colidx->h load chain); transform2 -> 32 rows/block
//     (4x less W2 refetch), padded LDS stride 68 (bank-conflict-free).
// ---------------------------------------------------------------------------

__global__ __launch_bounds__(256) void zero_i32(int* p, int n) {
    int i = blockIdx.x * 256 + threadIdx.x;
    if (i < n) p[i] = 0;
}

__global__ __launch_bounds__(256) void count_deg(const int* __restrict__ dst,
                                                 int* __restrict__ deg, int e) {
    int i = blockIdx.x * 256 + threadIdx.x;
    if (i < e) atomicAdd(&deg[dst[i]], 1);
}

// ---- scan: 1024 elems/block, 3 kernels ----
__global__ __launch_bounds__(256) void scan_partial(const int* __restrict__ deg,
                                                    int* __restrict__ bsums, int n) {
    __shared__ int sd[256];
    int t = threadIdx.x;
    int base = blockIdx.x * 1024 + t * 4;
    int s = 0;
#pragma unroll
    for (int j = 0; j < 4; j++)
        if (base + j < n) s += deg[base + j];
    sd[t] = s;
    __syncthreads();
    for (int off = 128; off > 0; off >>= 1) {
        if (t < off) sd[t] += sd[t + off];
        __syncthreads();
    }
    if (t == 0) bsums[blockIdx.x] = sd[0];
}

__global__ __launch_bounds__(256) void scan_blocksums(int* __restrict__ bs, int nb,
                                                      int* __restrict__ rowptr, int n) {
    __shared__ int s[256];
    int t = threadIdx.x;
    s[t] = (t < nb) ? bs[t] : 0;
    __syncthreads();
    for (int off = 1; off < 256; off <<= 1) {
        int u = (t >= off) ? s[t - off] : 0;
        __syncthreads();
        s[t] += u;
        __syncthreads();
    }
    if (t < nb) bs[t] = (t > 0) ? s[t - 1] : 0;  // exclusive block offsets
    if (t == 0) rowptr[n] = s[255];              // total = E
}

__global__ __launch_bounds__(256) void scan_final(const int* __restrict__ deg,
                                                  const int* __restrict__ bs,
                                                  int* __restrict__ rowptr,
                                                  int* __restrict__ fillc,
                                                  float* __restrict__ dinv, int n) {
    __shared__ int sd[256];
    int t = threadIdx.x;
    int base = blockIdx.x * 1024 + t * 4;
    int v0 = 0, v1 = 0, v2 = 0, v3 = 0;
    if (base + 0 < n) v0 = deg[base + 0];
    if (base + 1 < n) v1 = deg[base + 1];
    if (base + 2 < n) v2 = deg[base + 2];
    if (base + 3 < n) v3 = deg[base + 3];
    sd[t] = v0 + v1 + v2 + v3;
    __syncthreads();
    for (int off = 1; off < 256; off <<= 1) {
        int u = (t >= off) ? sd[t - off] : 0;
        __syncthreads();
        sd[t] += u;
        __syncthreads();
    }
    int run = bs[blockIdx.x] + ((t > 0) ? sd[t - 1] : 0);
    if (base + 0 < n) { rowptr[base + 0] = run; fillc[base + 0] = run; dinv[base + 0] = rsqrtf((float)(v0 + 1)); run += v0; }
    if (base + 1 < n) { rowptr[base + 1] = run; fillc[base + 1] = run; dinv[base + 1] = rsqrtf((float)(v1 + 1)); run += v1; }
    if (base + 2 < n) { rowptr[base + 2] = run; fillc[base + 2] = run; dinv[base + 2] = rsqrtf((float)(v2 + 1)); run += v2; }
    if (base + 3 < n) { rowptr[base + 3] = run; fillc[base + 3] = run; dinv[base + 3] = rsqrtf((float)(v3 + 1)); run += v3; }
}

__global__ __launch_bounds__(256) void fill_csr(const int* __restrict__ src,
                                                const int* __restrict__ dst,
                                                int* __restrict__ fillc,
                                                int* __restrict__ colidx, int e) {
    int i = blockIdx.x * 256 + threadIdx.x;
    if (i < e) {
        int d = dst[i];
        int p = atomicAdd(&fillc[d], 1);
        colidx[p] = src[i];
    }
}

// ---- transform 1 (tiled): h1 = dinv .* (x @ W1), x:(n,512) W1:(512,64) ----
__global__ __launch_bounds__(256) void transform1_tiled(const float* __restrict__ x,
                                                        const float* __restrict__ W1,
                                                        const float* __restrict__ dinv,
                                                        float* __restrict__ h1, int n) {
    __shared__ float As[32 * 68];  // As[k*68 + m]
    __shared__ float Bs[32 * 64];  // Bs[k*64 + j]
    const int t = threadIdx.x;
    const int row0 = blockIdx.x * 64;
    const int mt = (t >> 4) * 4;   // 0,4,...,60  (output row group)
    const int jt = (t & 15) * 4;   // 0,4,...,60  (output col group)
    float acc[4][4] = {};

    for (int k0 = 0; k0 < 512; k0 += 32) {
        __syncthreads();
#pragma unroll
        for (int i = 0; i < 2; i++) {
            int c = t + i * 256;
            int m = c >> 3;
            int kc = (c & 7) << 2;
            int grow = row0 + m;
            float4 v = make_float4(0.f, 0.f, 0.f, 0.f);
            if (grow < n) v = *(const float4*)&x[(size_t)grow * 512 + k0 + kc];
            As[(kc + 0) * 68 + m] = v.x;
            As[(kc + 1) * 68 + m] = v.y;
            As[(kc + 2) * 68 + m] = v.z;
            As[(kc + 3) * 68 + m] = v.w;
        }
#pragma unroll
        for (int i = 0; i < 2; i++) {
            int c = t + i * 256;
            int kr = c >> 4;
            int jc = (c & 15) << 2;
            *(float4*)&Bs[kr * 64 + jc] = *(const float4*)&W1[(size_t)(k0 + kr) * 64 + jc];
        }
        __syncthreads();
#pragma unroll
        for (int kk = 0; kk < 32; kk++) {
            float4 a = *(const float4*)&As[kk * 68 + mt];
            float4 b = *(const float4*)&Bs[kk * 64 + jt];
            acc[0][0] += a.x * b.x; acc[0][1] += a.x * b.y; acc[0][2] += a.x * b.z; acc[0][3] += a.x * b.w;
            acc[1][0] += a.y * b.x; acc[1][1] += a.y * b.y; acc[1][2] += a.y * b.z; acc[1][3] += a.y * b.w;
            acc[2][0] += a.z * b.x; acc[2][1] += a.z * b.y; acc[2][2] += a.z * b.z; acc[2][3] += a.z * b.w;
            acc[3][0] += a.w * b.x; acc[3][1] += a.w * b.y; acc[3][2] += a.w * b.z; acc[3][3] += a.w * b.w;
        }
    }
#pragma unroll
    for (int i = 0; i < 4; i++) {
        int row = row0 + mt + i;
        if (row < n) {
            float s = dinv[row];
            float4 o = make_float4(acc[i][0] * s, acc[i][1] * s, acc[i][2] * s, acc[i][3] * s);
            *(float4*)&h1[(size_t)row * 64 + jt] = o;
        }
    }
}

// ---- transform 2: h2 = dinv .* (g1 @ W2), g1:(n,64) W2:(64,32) ----
// 32 rows/block; thread -> 1 row x 4 cols; LDS row stride 68 (no conflicts);
// W2 reads are float4 and group-broadcast.
__global__ __launch_bounds__(256) void transform2(const float* __restrict__ g1,
                                                  const float* __restrict__ W2,
                                                  const float* __restrict__ dinv,
                                                  float* __restrict__ h2, int n) {
    __shared__ float rows[32 * 68];
    __shared__ float W2s[64 * 32];
    int t = threadIdx.x;
    int row0 = blockIdx.x * 32;
#pragma unroll
    for (int i = 0; i < 2; i++) {          // 32 rows x 64 = 512 float4
        int c = t + i * 256;
        int r = c >> 4, k4 = (c & 15) << 2;
        int grow = row0 + r;
        float4 v = make_float4(0.f, 0.f, 0.f, 0.f);
        if (grow < n) v = *(const float4*)&g1[(size_t)grow * 64 + k4];
        *(float4*)&rows[r * 68 + k4] = v;
    }
#pragma unroll
    for (int i = 0; i < 2; i++) {          // W2: 2048 floats = 512 float4
        int c = t + i * 256;
        *(float4*)&W2s[c * 4] = *(const float4*)&W2[c * 4];
    }
    __syncthreads();
    int lr = t >> 3;                       // 0..31 (row)
    int c4 = (t & 7) * 4;                  // 0,4,...,28 (col group)
    int row = row0 + lr;
    float a0 = 0.f, a1 = 0.f, a2 = 0.f, a3 = 0.f;
#pragma unroll
    for (int k4 = 0; k4 < 64; k4 += 4) {
        float4 a = *(const float4*)&rows[lr * 68 + k4];
        float4 w0 = *(const float4*)&W2s[(k4 + 0) * 32 + c4];
        float4 w1 = *(const float4*)&W2s[(k4 + 1) * 32 + c4];
        float4 w2 = *(const float4*)&W2s[(k4 + 2) * 32 + c4];
        float4 w3 = *(const float4*)&W2s[(k4 + 3) * 32 + c4];
        a0 += a.x * w0.x + a.y * w1.x + a.z * w2.x + a.w * w3.x;
        a1 += a.x * w0.y + a.y * w1.y + a.z * w2.y + a.w * w3.y;
        a2 += a.x * w0.z + a.y * w1.z + a.z * w2.z + a.w * w3.z;
        a3 += a.x * w0.w + a.y * w1.w + a.z * w2.w + a.w * w3.w;
    }
    if (row < n) {
        float s = dinv[row];
        float4 o = make_float4(a0 * s, a1 * s, a2 * s, a3 * s);
        *(float4*)&h2[(size_t)row * 32 + c4] = o;
    }
}

// ---- transform 3: h3 = dinv .* (g2 @ W3), g2:(n,32) W3:(32,4). thread/row ----
__global__ __launch_bounds__(256) void transform3(const float* __restrict__ g2,
                                                  const float* __restrict__ W3,
                                                  const float* __restrict__ dinv,
                                                  float* __restrict__ h3, int n) {
    __shared__ float W3s[128];
    int t = threadIdx.x;
    if (t < 128) W3s[t] = W3[t];
    __syncthreads();
    int row = blockIdx.x * 256 + t;
    if (row >= n) return;
    float a0 = 0.f, a1 = 0.f, a2 = 0.f, a3 = 0.f;
    const float4* rp = (const float4*)&g2[(size_t)row * 32];
#pragma unroll
    for (int kk = 0; kk < 8; kk++) {
        float4 v = rp[kk];
        float4 w0 = *(const float4*)&W3s[(4 * kk + 0) * 4];
        float4 w1 = *(const float4*)&W3s[(4 * kk + 1) * 4];
        float4 w2 = *(const float4*)&W3s[(4 * kk + 2) * 4];
        float4 w3 = *(const float4*)&W3s[(4 * kk + 3) * 4];
        a0 += v.x * w0.x + v.y * w1.x + v.z * w2.x + v.w * w3.x;
        a1 += v.x * w0.y + v.y * w1.y + v.z * w2.y + v.w * w3.y;
        a2 += v.x * w0.z + v.y * w1.z + v.z * w2.z + v.w * w3.z;
        a3 += v.x * w0.w + v.y * w1.w + v.z * w2.w + v.w * w3.w;
    }
    float s = dinv[row];
    float4 o = make_float4(a0 * s, a1 * s, a2 * s, a3 * s);
    *(float4*)&h3[(size_t)row * 4] = o;
}

// ---- aggregation (ILP): F-lane group per node, 8-way edge unroll ----
// out[d][f] = (RELU?)( dinv[d] * (sum_{e} h[col[e]][f] + h[d][f]) + bias[f] )
// 8 independent accumulators -> 8 gathers in flight per group.
template <int F, bool RELU>
__global__ __launch_bounds__(256) void aggregate_ilp(const float* __restrict__ h,
                                                     const int* __restrict__ rowptr,
                                                     const int* __restrict__ colidx,
                                                     const float* __restrict__ dinv,
                                                     const float* __restrict__ bias,
                                                     float* __restrict__ out, int n) {
    int tid = blockIdx.x * 256 + threadIdx.x;
    int node = tid / F;
    int f = tid & (F - 1);
    if (node >= n) return;
    int r0 = rowptr[node], r1 = rowptr[node + 1];
    float acc0 = h[(size_t)node * F + f];  // self loop
    float acc1 = 0.f, acc2 = 0.f, acc3 = 0.f;
    float acc4 = 0.f, acc5 = 0.f, acc6 = 0.f, acc7 = 0.f;
    int j = r0;
    for (; j + 7 < r1; j += 8) {
        int c0 = colidx[j + 0];
        int c1 = colidx[j + 1];
        int c2 = colidx[j + 2];
        int c3 = colidx[j + 3];
        int c4 = colidx[j + 4];
        int c5 = colidx[j + 5];
        int c6 = colidx[j + 6];
        int c7 = colidx[j + 7];
        acc0 += h[(size_t)c0 * F + f];
        acc1 += h[(size_t)c1 * F + f];
        acc2 += h[(size_t)c2 * F + f];
        acc3 += h[(size_t)c3 * F + f];
        acc4 += h[(size_t)c4 * F + f];
        acc5 += h[(size_t)c5 * F + f];
        acc6 += h[(size_t)c6 * F + f];
        acc7 += h[(size_t)c7 * F + f];
    }
    for (; j < r1; j++) {
        acc0 += h[(size_t)colidx[j] * F + f];
    }
    float acc = ((acc0 + acc1) + (acc2 + acc3)) + ((acc4 + acc5) + (acc6 + acc7));
    float v = dinv[node] * acc + bias[f];
    if (RELU) v = fmaxf(v, 0.f);
    out[(size_t)node * F + f] = v;
}

extern "C" void kernel_launch(void* const* d_in, const int* in_sizes, int n_in,
                              void* d_out, int out_size, void* d_ws, size_t ws_size,
                              hipStream_t stream) {
    const float* x  = (const float*)d_in[0];
    const int*   ei = (const int*)d_in[1];
    const float* W1 = (const float*)d_in[2];
    const float* b1 = (const float*)d_in[3];
    const float* W2 = (const float*)d_in[4];
    const float* b2 = (const float*)d_in[5];
    const float* W3 = (const float*)d_in[6];
    const float* b3 = (const float*)d_in[7];
    const int n = in_sizes[0] / 512;  // 100000
    const int e = in_sizes[1] / 2;    // 1600000
    const int* src = ei;
    const int* dst = ei + e;
    float* out = (float*)d_out;

    char* p = (char*)d_ws;
    auto alloc = [&](size_t bytes) {
        void* r = (void*)p;
        p += (bytes + 255) & ~(size_t)255;
        return r;
    };
    int*   deg    = (int*)alloc((size_t)n * 4);
    int*   rowptr = (int*)alloc((size_t)(n + 1) * 4);
    int*   fillc  = (int*)alloc((size_t)n * 4);
    int*   bsums  = (int*)alloc(1024);
    int*   colidx = (int*)alloc((size_t)e * 4);
    float* dinv   = (float*)alloc((size_t)n * 4);
    float* bufA   = (float*)alloc((size_t)n * 64 * 4);
    float* bufB   = (float*)alloc((size_t)n * 64 * 4);

    const int NB = (n + 1023) / 1024;  // 98 scan blocks

    zero_i32<<<dim3((n + 255) / 256), dim3(256), 0, stream>>>(deg, n);
    count_deg<<<dim3((e + 255) / 256), dim3(256), 0, stream>>>(dst, deg, e);
    scan_partial<<<dim3(NB), dim3(256), 0, stream>>>(deg, bsums, n);
    scan_blocksums<<<dim3(1), dim3(256), 0, stream>>>(bsums, NB, rowptr, n);
    scan_final<<<dim3(NB), dim3(256), 0, stream>>>(deg, bsums, rowptr, fillc, dinv, n);
    fill_csr<<<dim3((e + 255) / 256), dim3(256), 0, stream>>>(src, dst, fillc, colidx, e);

    // layer 1: transform (n,512)->(n,64), aggregate, relu
    transform1_tiled<<<dim3((n + 63) / 64), dim3(256), 0, stream>>>(x, W1, dinv, bufA, n);
    aggregate_ilp<64, true><<<dim3((int)(((size_t)n * 64 + 255) / 256)), dim3(256), 0, stream>>>(bufA, rowptr, colidx, dinv, b1, bufB, n);
    // layer 2: (n,64)->(n,32)
    transform2<<<dim3((n + 31) / 32), dim3(256), 0, stream>>>(bufB, W2, dinv, bufA, n);
    aggregate_ilp<32, true><<<dim3((int)(((size_t)n * 32 + 255) / 256)), dim3(256), 0, stream>>>(bufA, rowptr, colidx, dinv, b2, bufB, n);
    // layer 3: (n,32)->(n,4), no relu
    transform3<<<dim3((n + 255) / 256), dim3(256), 0, stream>>>(bufB, W3, dinv, bufA, n);
    aggregate_ilp<4, false><<<dim3((int)(((size_t)n * 4 + 255) / 256)), dim3(256), 0, stream>>>(bufA, rowptr, colidx, dinv, b3, out, n);
}

// Round 5
// 668.664 us; speedup vs baseline: 2.2831x; 1.0015x over previous
//
#include <hip/hip_runtime.h>

// ---------------------------------------------------------------------------
// GCN 3-layer: h = relu(Agg(dinv*x@W1)+b1); h = relu(Agg(dinv*h@W2)+b2);
//              out = Agg(dinv*h@W3)+b3
// Agg(y)[d] = dinv[d] * ( sum_{e: dst=d} y[src_e] + y[d] )   (self-loop folded)
// R5: transform1 -> split-bf16 MFMA (x=hi+lo, 3 mfma, fp32-accurate to ~6e-5);
//     fill_csr/count_deg -> 4 edges/thread (atomic MLP x4).
// ---------------------------------------------------------------------------

typedef __attribute__((ext_vector_type(8))) short short8;
typedef __attribute__((ext_vector_type(4))) float floatx4;

__device__ __forceinline__ unsigned f2bf_bits(float f) {
    unsigned u = __float_as_uint(f);
    return (u + 0x7fffu + ((u >> 16) & 1u)) >> 16;  // RNE
}
__device__ __forceinline__ float bf_bits2f(unsigned b) {
    return __uint_as_float(b << 16);
}

__global__ __launch_bounds__(256) void zero_i32(int* p, int n) {
    int i = blockIdx.x * 256 + threadIdx.x;
    if (i < n) p[i] = 0;
}

__global__ __launch_bounds__(256) void count_deg4(const int* __restrict__ dst,
                                                  int* __restrict__ deg, int e) {
    int i0 = (blockIdx.x * 256 + threadIdx.x) * 4;
    if (i0 + 3 < e) {
        int4 d4 = *(const int4*)&dst[i0];
        atomicAdd(&deg[d4.x], 1);
        atomicAdd(&deg[d4.y], 1);
        atomicAdd(&deg[d4.z], 1);
        atomicAdd(&deg[d4.w], 1);
    } else {
        for (int i = i0; i < e; i++) atomicAdd(&deg[dst[i]], 1);
    }
}

// ---- scan: 1024 elems/block, 3 kernels ----
__global__ __launch_bounds__(256) void scan_partial(const int* __restrict__ deg,
                                                    int* __restrict__ bsums, int n) {
    __shared__ int sd[256];
    int t = threadIdx.x;
    int base = blockIdx.x * 1024 + t * 4;
    int s = 0;
#pragma unroll
    for (int j = 0; j < 4; j++)
        if (base + j < n) s += deg[base + j];
    sd[t] = s;
    __syncthreads();
    for (int off = 128; off > 0; off >>= 1) {
        if (t < off) sd[t] += sd[t + off];
        __syncthreads();
    }
    if (t == 0) bsums[blockIdx.x] = sd[0];
}

__global__ __launch_bounds__(256) void scan_blocksums(int* __restrict__ bs, int nb,
                                                      int* __restrict__ rowptr, int n) {
    __shared__ int s[256];
    int t = threadIdx.x;
    s[t] = (t < nb) ? bs[t] : 0;
    __syncthreads();
    for (int off = 1; off < 256; off <<= 1) {
        int u = (t >= off) ? s[t - off] : 0;
        __syncthreads();
        s[t] += u;
        __syncthreads();
    }
    if (t < nb) bs[t] = (t > 0) ? s[t - 1] : 0;  // exclusive block offsets
    if (t == 0) rowptr[n] = s[255];              // total = E
}

__global__ __launch_bounds__(256) void scan_final(const int* __restrict__ deg,
                                                  const int* __restrict__ bs,
                                                  int* __restrict__ rowptr,
                                                  int* __restrict__ fillc,
                                                  float* __restrict__ dinv, int n) {
    __shared__ int sd[256];
    int t = threadIdx.x;
    int base = blockIdx.x * 1024 + t * 4;
    int v0 = 0, v1 = 0, v2 = 0, v3 = 0;
    if (base + 0 < n) v0 = deg[base + 0];
    if (base + 1 < n) v1 = deg[base + 1];
    if (base + 2 < n) v2 = deg[base + 2];
    if (base + 3 < n) v3 = deg[base + 3];
    sd[t] = v0 + v1 + v2 + v3;
    __syncthreads();
    for (int off = 1; off < 256; off <<= 1) {
        int u = (t >= off) ? sd[t - off] : 0;
        __syncthreads();
        sd[t] += u;
        __syncthreads();
    }
    int run = bs[blockIdx.x] + ((t > 0) ? sd[t - 1] : 0);
    if (base + 0 < n) { rowptr[base + 0] = run; fillc[base + 0] = run; dinv[base + 0] = rsqrtf((float)(v0 + 1)); run += v0; }
    if (base + 1 < n) { rowptr[base + 1] = run; fillc[base + 1] = run; dinv[base + 1] = rsqrtf((float)(v1 + 1)); run += v1; }
    if (base + 2 < n) { rowptr[base + 2] = run; fillc[base + 2] = run; dinv[base + 2] = rsqrtf((float)(v2 + 1)); run += v2; }
    if (base + 3 < n) { rowptr[base + 3] = run; fillc[base + 3] = run; dinv[base + 3] = rsqrtf((float)(v3 + 1)); run += v3; }
}

__global__ __launch_bounds__(256) void fill_csr4(const int* __restrict__ src,
                                                 const int* __restrict__ dst,
                                                 int* __restrict__ fillc,
                                                 int* __restrict__ colidx, int e) {
    int i0 = (blockIdx.x * 256 + threadIdx.x) * 4;
    if (i0 + 3 < e) {
        int4 d4 = *(const int4*)&dst[i0];
        int4 s4 = *(const int4*)&src[i0];
        int p0 = atomicAdd(&fillc[d4.x], 1);
        int p1 = atomicAdd(&fillc[d4.y], 1);
        int p2 = atomicAdd(&fillc[d4.z], 1);
        int p3 = atomicAdd(&fillc[d4.w], 1);
        colidx[p0] = s4.x;
        colidx[p1] = s4.y;
        colidx[p2] = s4.z;
        colidx[p3] = s4.w;
    } else {
        for (int i = i0; i < e; i++) {
            int d = dst[i];
            int p = atomicAdd(&fillc[d], 1);
            colidx[p] = src[i];
        }
    }
}

// ---- W1 split into hi/lo bf16, pre-swizzled into B-fragment order ----
// B-frag for 16x16x32: lane holds B[k=quad*8+j][n=lane&15], quad=lane>>4.
// Storage: whi[((ct*16+kc)*64+lane)*8 + j], ct=n>>4, kc=k>>5.
__global__ __launch_bounds__(256) void w1_split(const float* __restrict__ W1,
                                                short* __restrict__ whi,
                                                short* __restrict__ wlo) {
    int idx = blockIdx.x * 256 + threadIdx.x;  // 0..32767
    int k = idx >> 6;
    int nn = idx & 63;
    float v = W1[idx];
    unsigned hb = f2bf_bits(v);
    float lof = v - bf_bits2f(hb);
    unsigned lb = f2bf_bits(lof);
    int kc = k >> 5, rem = k & 31, quad = rem >> 3, j = rem & 7;
    int ct = nn >> 4, l = nn & 15;
    int lane = quad * 16 + l;
    int addr = ((ct * 16 + kc) * 64 + lane) * 8 + j;
    whi[addr] = (short)hb;
    wlo[addr] = (short)lb;
}

// ---- transform 1 (MFMA): h1 = dinv .* (x @ W1), x:(n,512) W1:(512,64) ----
// 64 rows x 64 cols per block (4 waves; wave w -> rows w*16..w*16+15, all 64
// cols as 4 col-tiles). Split-bf16: x = ahi + alo; 3 MFMAs (hi*hi, lo*hi,
// hi*lo) recover fp32 accuracy to ~2^-16 input rounding.
__global__ __launch_bounds__(256) void transform1_mfma(const float* __restrict__ x,
                                                       const short* __restrict__ whi,
                                                       const short* __restrict__ wlo,
                                                       const float* __restrict__ dinv,
                                                       float* __restrict__ h1, int n) {
    __shared__ float xs[64 * 36];  // [m][k] row-major, stride 36 (144B, 16B-aligned)
    const int t = threadIdx.x;
    const int w = t >> 6;
    const int lane = t & 63;
    const int quad = lane >> 4;
    const int row0 = blockIdx.x * 64;
    const int mrow = w * 16 + (lane & 15);  // A-frag row within block tile
    floatx4 acc[4] = {{0.f, 0.f, 0.f, 0.f}, {0.f, 0.f, 0.f, 0.f},
                      {0.f, 0.f, 0.f, 0.f}, {0.f, 0.f, 0.f, 0.f}};

    for (int kc = 0; kc < 16; kc++) {
        __syncthreads();
        // stage x tile: 64 rows x 32 k = 512 float4
#pragma unroll
        for (int i = 0; i < 2; i++) {
            int c = t + i * 256;
            int m = c >> 3;
            int koff = (c & 7) << 2;
            int grow = row0 + m;
            float4 v = make_float4(0.f, 0.f, 0.f, 0.f);
            if (grow < n) v = *(const float4*)&x[(size_t)grow * 512 + kc * 32 + koff];
            *(float4*)&xs[m * 36 + koff] = v;
        }
        __syncthreads();
        // A fragment: 8 consecutive k at row mrow, k-offset quad*8
        float a[8];
        *(float4*)&a[0] = *(const float4*)&xs[mrow * 36 + quad * 8];
        *(float4*)&a[4] = *(const float4*)&xs[mrow * 36 + quad * 8 + 4];
        short8 ahi, alo;
#pragma unroll
        for (int j = 0; j < 8; j++) {
            unsigned hb = f2bf_bits(a[j]);
            float lof = a[j] - bf_bits2f(hb);
            unsigned lb = f2bf_bits(lof);
            ahi[j] = (short)hb;
            alo[j] = (short)lb;
        }
        const int base = (kc * 64 + lane) * 8;  // + ct*8192
#pragma unroll
        for (int ct = 0; ct < 4; ct++) {
            short8 bhi = *(const short8*)&whi[ct * 8192 + base];
            short8 blo = *(const short8*)&wlo[ct * 8192 + base];
            acc[ct] = __builtin_amdgcn_mfma_f32_16x16x32_bf16(ahi, bhi, acc[ct], 0, 0, 0);
            acc[ct] = __builtin_amdgcn_mfma_f32_16x16x32_bf16(alo, bhi, acc[ct], 0, 0, 0);
            acc[ct] = __builtin_amdgcn_mfma_f32_16x16x32_bf16(ahi, blo, acc[ct], 0, 0, 0);
        }
    }
    // epilogue: D[row=quad*4+r][col=lane&15]
#pragma unroll
    for (int r = 0; r < 4; r++) {
        int grow = row0 + w * 16 + quad * 4 + r;
        if (grow < n) {
            float s = dinv[grow];
#pragma unroll
            for (int ct = 0; ct < 4; ct++) {
                h1[(size_t)grow * 64 + ct * 16 + (lane & 15)] = acc[ct][r] * s;
            }
        }
    }
}

// ---- transform 2: h2 = dinv .* (g1 @ W2), g1:(n,64) W2:(64,32) ----
__global__ __launch_bounds__(256) void transform2(const float* __restrict__ g1,
                                                  const float* __restrict__ W2,
                                                  const float* __restrict__ dinv,
                                                  float* __restrict__ h2, int n) {
    __shared__ float rows[32 * 68];
    __shared__ float W2s[64 * 32];
    int t = threadIdx.x;
    int row0 = blockIdx.x * 32;
#pragma unroll
    for (int i = 0; i < 2; i++) {          // 32 rows x 64 = 512 float4
        int c = t + i * 256;
        int r = c >> 4, k4 = (c & 15) << 2;
        int grow = row0 + r;
        float4 v = make_float4(0.f, 0.f, 0.f, 0.f);
        if (grow < n) v = *(const float4*)&g1[(size_t)grow * 64 + k4];
        *(float4*)&rows[r * 68 + k4] = v;
    }
#pragma unroll
    for (int i = 0; i < 2; i++) {          // W2: 2048 floats = 512 float4
        int c = t + i * 256;
        *(float4*)&W2s[c * 4] = *(const float4*)&W2[c * 4];
    }
    __syncthreads();
    int lr = t >> 3;                       // 0..31 (row)
    int c4 = (t & 7) * 4;                  // 0,4,...,28 (col group)
    int row = row0 + lr;
    float a0 = 0.f, a1 = 0.f, a2 = 0.f, a3 = 0.f;
#pragma unroll
    for (int k4 = 0; k4 < 64; k4 += 4) {
        float4 a = *(const float4*)&rows[lr * 68 + k4];
        float4 w0 = *(const float4*)&W2s[(k4 + 0) * 32 + c4];
        float4 w1 = *(const float4*)&W2s[(k4 + 1) * 32 + c4];
        float4 w2 = *(const float4*)&W2s[(k4 + 2) * 32 + c4];
        float4 w3 = *(const float4*)&W2s[(k4 + 3) * 32 + c4];
        a0 += a.x * w0.x + a.y * w1.x + a.z * w2.x + a.w * w3.x;
        a1 += a.x * w0.y + a.y * w1.y + a.z * w2.y + a.w * w3.y;
        a2 += a.x * w0.z + a.y * w1.z + a.z * w2.z + a.w * w3.z;
        a3 += a.x * w0.w + a.y * w1.w + a.z * w2.w + a.w * w3.w;
    }
    if (row < n) {
        float s = dinv[row];
        float4 o = make_float4(a0 * s, a1 * s, a2 * s, a3 * s);
        *(float4*)&h2[(size_t)row * 32 + c4] = o;
    }
}

// ---- transform 3: h3 = dinv .* (g2 @ W3), g2:(n,32) W3:(32,4). thread/row ----
__global__ __launch_bounds__(256) void transform3(const float* __restrict__ g2,
                                                  const float* __restrict__ W3,
                                                  const float* __restrict__ dinv,
                                                  float* __restrict__ h3, int n) {
    __shared__ float W3s[128];
    int t = threadIdx.x;
    if (t < 128) W3s[t] = W3[t];
    __syncthreads();
    int row = blockIdx.x * 256 + t;
    if (row >= n) return;
    float a0 = 0.f, a1 = 0.f, a2 = 0.f, a3 = 0.f;
    const float4* rp = (const float4*)&g2[(size_t)row * 32];
#pragma unroll
    for (int kk = 0; kk < 8; kk++) {
        float4 v = rp[kk];
        float4 w0 = *(const float4*)&W3s[(4 * kk + 0) * 4];
        float4 w1 = *(const float4*)&W3s[(4 * kk + 1) * 4];
        float4 w2 = *(const float4*)&W3s[(4 * kk + 2) * 4];
        float4 w3 = *(const float4*)&W3s[(4 * kk + 3) * 4];
        a0 += v.x * w0.x + v.y * w1.x + v.z * w2.x + v.w * w3.x;
        a1 += v.x * w0.y + v.y * w1.y + v.z * w2.y + v.w * w3.y;
        a2 += v.x * w0.z + v.y * w1.z + v.z * w2.z + v.w * w3.z;
        a3 += v.x * w0.w + v.y * w1.w + v.z * w2.w + v.w * w3.w;
    }
    float s = dinv[row];
    float4 o = make_float4(a0 * s, a1 * s, a2 * s, a3 * s);
    *(float4*)&h3[(size_t)row * 4] = o;
}

// ---- aggregation (ILP): F-lane group per node, 8-way edge unroll ----
template <int F, bool RELU>
__global__ __launch_bounds__(256) void aggregate_ilp(const float* __restrict__ h,
                                                     const int* __restrict__ rowptr,
                                                     const int* __restrict__ colidx,
                                                     const float* __restrict__ dinv,
                                                     const float* __restrict__ bias,
                                                     float* __restrict__ out, int n) {
    int tid = blockIdx.x * 256 + threadIdx.x;
    int node = tid / F;
    int f = tid & (F - 1);
    if (node >= n) return;
    int r0 = rowptr[node], r1 = rowptr[node + 1];
    float acc0 = h[(size_t)node * F + f];  // self loop
    float acc1 = 0.f, acc2 = 0.f, acc3 = 0.f;
    float acc4 = 0.f, acc5 = 0.f, acc6 = 0.f, acc7 = 0.f;
    int j = r0;
    for (; j + 7 < r1; j += 8) {
        int c0 = colidx[j + 0];
        int c1 = colidx[j + 1];
        int c2 = colidx[j + 2];
        int c3 = colidx[j + 3];
        int c4 = colidx[j + 4];
        int c5 = colidx[j + 5];
        int c6 = colidx[j + 6];
        int c7 = colidx[j + 7];
        acc0 += h[(size_t)c0 * F + f];
        acc1 += h[(size_t)c1 * F + f];
        acc2 += h[(size_t)c2 * F + f];
        acc3 += h[(size_t)c3 * F + f];
        acc4 += h[(size_t)c4 * F + f];
        acc5 += h[(size_t)c5 * F + f];
        acc6 += h[(size_t)c6 * F + f];
        acc7 += h[(size_t)c7 * F + f];
    }
    for (; j < r1; j++) {
        acc0 += h[(size_t)colidx[j] * F + f];
    }
    float acc = ((acc0 + acc1) + (acc2 + acc3)) + ((acc4 + acc5) + (acc6 + acc7));
    float v = dinv[node] * acc + bias[f];
    if (RELU) v = fmaxf(v, 0.f);
    out[(size_t)node * F + f] = v;
}

extern "C" void kernel_launch(void* const* d_in, const int* in_sizes, int n_in,
                              void* d_out, int out_size, void* d_ws, size_t ws_size,
                              hipStream_t stream) {
    const float* x  = (const float*)d_in[0];
    const int*   ei = (const int*)d_in[1];
    const float* W1 = (const float*)d_in[2];
    const float* b1 = (const float*)d_in[3];
    const float* W2 = (const float*)d_in[4];
    const float* b2 = (const float*)d_in[5];
    const float* W3 = (const float*)d_in[6];
    const float* b3 = (const float*)d_in[7];
    const int n = in_sizes[0] / 512;  // 100000
    const int e = in_sizes[1] / 2;    // 1600000
    const int* src = ei;
    const int* dst = ei + e;
    float* out = (float*)d_out;

    char* p = (char*)d_ws;
    auto alloc = [&](size_t bytes) {
        void* r = (void*)p;
        p += (bytes + 255) & ~(size_t)255;
        return r;
    };
    int*   deg    = (int*)alloc((size_t)n * 4);
    int*   rowptr = (int*)alloc((size_t)(n + 1) * 4);
    int*   fillc  = (int*)alloc((size_t)n * 4);
    int*   bsums  = (int*)alloc(1024);
    int*   colidx = (int*)alloc((size_t)e * 4);
    float* dinv   = (float*)alloc((size_t)n * 4);
    short* whi    = (short*)alloc((size_t)32768 * 2);
    short* wlo    = (short*)alloc((size_t)32768 * 2);
    float* bufA   = (float*)alloc((size_t)n * 64 * 4);
    float* bufB   = (float*)alloc((size_t)n * 64 * 4);

    const int NB = (n + 1023) / 1024;  // 98 scan blocks
    const int E4 = (e / 4 + 255) / 256;

    zero_i32<<<dim3((n + 255) / 256), dim3(256), 0, stream>>>(deg, n);
    count_deg4<<<dim3(E4), dim3(256), 0, stream>>>(dst, deg, e);
    scan_partial<<<dim3(NB), dim3(256), 0, stream>>>(deg, bsums, n);
    scan_blocksums<<<dim3(1), dim3(256), 0, stream>>>(bsums, NB, rowptr, n);
    scan_final<<<dim3(NB), dim3(256), 0, stream>>>(deg, bsums, rowptr, fillc, dinv, n);
    fill_csr4<<<dim3(E4), dim3(256), 0, stream>>>(src, dst, fillc, colidx, e);
    w1_split<<<dim3(128), dim3(256), 0, stream>>>(W1, whi, wlo);

    // layer 1: transform (n,512)->(n,64), aggregate, relu
    transform1_mfma<<<dim3((n + 63) / 64), dim3(256), 0, stream>>>(x, whi, wlo, dinv, bufA, n);
    aggregate_ilp<64, true><<<dim3((int)(((size_t)n * 64 + 255) / 256)), dim3(256), 0, stream>>>(bufA, rowptr, colidx, dinv, b1, bufB, n);
    // layer 2: (n,64)->(n,32)
    transform2<<<dim3((n + 31) / 32), dim3(256), 0, stream>>>(bufB, W2, dinv, bufA, n);
    aggregate_ilp<32, true><<<dim3((int)(((size_t)n * 32 + 255) / 256)), dim3(256), 0, stream>>>(bufA, rowptr, colidx, dinv, b2, bufB, n);
    // layer 3: (n,32)->(n,4), no relu
    transform3<<<dim3((n + 255) / 256), dim3(256), 0, stream>>>(bufB, W3, dinv, bufA, n);
    aggregate_ilp<4, false><<<dim3((int)(((size_t)n * 4 + 255) / 256)), dim3(256), 0, stream>>>(bufA, rowptr, colidx, dinv, b3, out, n);
}